// Round 1
// baseline (315.689 us; speedup 1.0000x reference)
//
#include <hip/hip_runtime.h>

typedef __attribute__((ext_vector_type(8))) short s16x8;
typedef __attribute__((ext_vector_type(4))) short s16x4;
typedef __attribute__((ext_vector_type(4))) float f32x4;

#define DEVI static __device__ __forceinline__

DEVI short f2bf(float f) {
  union { float f; unsigned u; } v; v.f = f;
  unsigned u = v.u;
  unsigned r = u + 0x7FFFu + ((u >> 16) & 1u);   // round-to-nearest-even
  return (short)(r >> 16);
}
DEVI float bf2f(short s) {
  union { unsigned u; float f; } v;
  v.u = ((unsigned)(unsigned short)s) << 16;
  return v.f;
}
DEVI f32x4 mfma16(s16x8 a, s16x8 b, f32x4 c) {
  return __builtin_amdgcn_mfma_f32_16x16x32_bf16(a, b, c, 0, 0, 0);
}

constexpr int Sc = 2048, Dc = 1024, Hc = 16, DKc = 64;
constexpr int Mc = 4096;             // B*S
constexpr int BM = 128, BN = 128, BKt = 64, LDA = BKt + 8;  // padded LDS stride

// ---------------- dtype detector -------------------------------------------
// fp32 N(0,1) data read as bf16 halfwords: low halves have uniform-random
// exponent -> ~22% of halfwords have exponent >= 140 (|v| >= 2^13).
// true bf16 N(0,1) data: exponent <= ~130 always.
__global__ void detect_ker(const unsigned short* __restrict__ x, int* __restrict__ flag) {
  __shared__ int cnt;
  if (threadIdx.x == 0) cnt = 0;
  __syncthreads();
  int c = 0;
  for (int i = threadIdx.x; i < 4096; i += 256) {
    int e = (x[i] >> 7) & 0xFF;
    if (e >= 140) c++;
  }
  atomicAdd(&cnt, c);
  __syncthreads();
  if (threadIdx.x == 0) *flag = (cnt > 64) ? 1 : 0;   // 1 = inputs are fp32
}

// ---------------- input normalizers ----------------------------------------
__global__ void norm_bf(const void* __restrict__ src, short* __restrict__ dst,
                        int n4, const int* __restrict__ flag) {
  int i = blockIdx.x * blockDim.x + threadIdx.x;
  if (i >= n4) return;
  if (*flag) {
    f32x4 v = ((const f32x4*)src)[i];
    s16x4 o;
#pragma unroll
    for (int j = 0; j < 4; ++j) o[j] = f2bf(v[j]);
    ((s16x4*)dst)[i] = o;
  } else {
    ((s16x4*)dst)[i] = ((const s16x4*)src)[i];
  }
}

__global__ void norm_bias(const void* __restrict__ src, float* __restrict__ dst,
                          const int* __restrict__ flag) {
  int f = *flag;
#pragma unroll
  for (int j = 0; j < 4; ++j) {
    int i = threadIdx.x + j * 256;
    dst[i] = f ? ((const float*)src)[i] : bf2f(((const short*)src)[i]);
  }
}

// ---------------- GEMM: C = A(MxK) * W(NxK)^T + bias ------------------------
// EPI==0: write bf16 in (B,H,S,DK) layout (QKV), scale Q tile by 1/8.
// EPI==1: write d_out row-major; fp32 if *flag else bf16.
template <int EPI>
__global__ __launch_bounds__(256, 2)
void gemm_bt(const short* __restrict__ A, const short* __restrict__ Wbase,
             const float* __restrict__ bias_c, short* __restrict__ outQKV,
             void* __restrict__ outFinal, const int* __restrict__ flag) {
  constexpr int K = Dc, N = Dc;
  const int z = blockIdx.z;
  const short* W = Wbase + (size_t)z * N * K;
  const float* bias = bias_c + (size_t)z * N;
  const float oscale = (EPI == 0 && z == 0) ? 0.125f : 1.0f;

  __shared__ short lA[BM][LDA];
  __shared__ short lB[BN][LDA];

  const int tid = threadIdx.x;
  const int lane = tid & 63, wave = tid >> 6;
  const int l16 = lane & 15, quad = lane >> 4;
  const int wm0 = (wave >> 1) * 64, wn0 = (wave & 1) * 64;
  const int m0 = blockIdx.y * BM, n0 = blockIdx.x * BN;

  f32x4 acc[4][4] = {};

  for (int k0 = 0; k0 < K; k0 += BKt) {
    __syncthreads();
#pragma unroll
    for (int it = 0; it < 4; ++it) {
      int chunk = tid + it * 256;
      int r = chunk >> 3, c = (chunk & 7) * 8;
      *(f32x4*)&lA[r][c] = *(const f32x4*)&A[(size_t)(m0 + r) * K + k0 + c];
      *(f32x4*)&lB[r][c] = *(const f32x4*)&W[(size_t)(n0 + r) * K + k0 + c];
    }
    __syncthreads();
#pragma unroll
    for (int ks = 0; ks < 2; ++ks) {
      s16x8 af[4], bfr[4];
#pragma unroll
      for (int i = 0; i < 4; ++i) {
        af[i]  = *(const s16x8*)&lA[wm0 + i * 16 + l16][ks * 32 + quad * 8];
        bfr[i] = *(const s16x8*)&lB[wn0 + i * 16 + l16][ks * 32 + quad * 8];
      }
#pragma unroll
      for (int mi = 0; mi < 4; ++mi)
#pragma unroll
        for (int ni = 0; ni < 4; ++ni)
          acc[mi][ni] = mfma16(af[mi], bfr[ni], acc[mi][ni]);
    }
  }

  int f32out = 0;
  if constexpr (EPI == 1) f32out = *flag;

#pragma unroll
  for (int ni = 0; ni < 4; ++ni) {
    int n = n0 + wn0 + ni * 16 + l16;
    float bv = bias[n];
#pragma unroll
    for (int mi = 0; mi < 4; ++mi) {
#pragma unroll
      for (int r = 0; r < 4; ++r) {
        int m = m0 + wm0 + mi * 16 + quad * 4 + r;
        float v = (acc[mi][ni][r] + bv) * oscale;
        if constexpr (EPI == 0) {
          // (B,H,S,DK): m = b*S+s, n = h*DK+dk
          int bb = m >> 11, s = m & 2047, h = n >> 6, dk = n & 63;
          size_t idx = ((((size_t)bb * Hc + h) * Sc) + s) * DKc + dk +
                       (size_t)z * Mc * N;
          outQKV[idx] = f2bf(v);
        } else {
          if (f32out) ((float*)outFinal)[(size_t)m * N + n] = v;
          else        ((short*)outFinal)[(size_t)m * N + n] = f2bf(v);
        }
      }
    }
  }
}

// ---------------- flash attention -------------------------------------------
// grid: x = q-tile (S/128), y = b*H + h. block = 256 (4 waves x 32 Q-rows).
__global__ __launch_bounds__(256, 2)
void attn_ker(const short* __restrict__ Q, const short* __restrict__ Kg,
              const short* __restrict__ Vg, short* __restrict__ O) {
  __shared__ short lK[64][72];
  __shared__ short lVt[64][72];     // transposed V: lVt[d][k]
  __shared__ short lP[4][32][72];   // per-wave P round-trip

  const int tid = threadIdx.x;
  const int lane = tid & 63, wave = tid >> 6;
  const int l16 = lane & 15, quad = lane >> 4;

  const int bh = blockIdx.y;
  const short* Qb = Q + (size_t)bh * Sc * DKc;
  const short* Kb = Kg + (size_t)bh * Sc * DKc;
  const short* Vb = Vg + (size_t)bh * Sc * DKc;

  const int q0 = blockIdx.x * 128 + wave * 32;

  s16x8 qf[2][2];
#pragma unroll
  for (int mi = 0; mi < 2; ++mi)
#pragma unroll
    for (int ks = 0; ks < 2; ++ks)
      qf[mi][ks] = *(const s16x8*)&Qb[(size_t)(q0 + mi * 16 + l16) * DKc + ks * 32 + quad * 8];

  float mst[2][4], lst[2][4];
  f32x4 oacc[2][4] = {};
#pragma unroll
  for (int mi = 0; mi < 2; ++mi)
#pragma unroll
    for (int r = 0; r < 4; ++r) { mst[mi][r] = -3.0e38f; lst[mi][r] = 0.f; }

  for (int kt = 0; kt < Sc / 64; ++kt) {
    const int kb = kt * 64;
    __syncthreads();
#pragma unroll
    for (int it = 0; it < 2; ++it) {
      int chunk = tid + it * 256;
      int r = chunk >> 3, c = (chunk & 7) * 8;
      *(f32x4*)&lK[r][c] = *(const f32x4*)&Kb[(size_t)(kb + r) * DKc + c];
      s16x8 v = *(const s16x8*)&Vb[(size_t)(kb + r) * DKc + c];
#pragma unroll
      for (int j = 0; j < 8; ++j) lVt[c + j][r] = v[j];
    }
    __syncthreads();

    // S = Q K^T  (Q pre-scaled by 1/8 in projection epilogue)
    f32x4 sacc[2][4] = {};
#pragma unroll
    for (int ks = 0; ks < 2; ++ks) {
      s16x8 kf[4];
#pragma unroll
      for (int ni = 0; ni < 4; ++ni)
        kf[ni] = *(const s16x8*)&lK[ni * 16 + l16][ks * 32 + quad * 8];
#pragma unroll
      for (int mi = 0; mi < 2; ++mi)
#pragma unroll
        for (int ni = 0; ni < 4; ++ni)
          sacc[mi][ni] = mfma16(qf[mi][ks], kf[ni], sacc[mi][ni]);
    }

    // online softmax (rows live in C-layout: row = quad*4+r, col = ni*16+l16)
#pragma unroll
    for (int mi = 0; mi < 2; ++mi) {
#pragma unroll
      for (int r = 0; r < 4; ++r) {
        float rmax = fmaxf(fmaxf(sacc[mi][0][r], sacc[mi][1][r]),
                           fmaxf(sacc[mi][2][r], sacc[mi][3][r]));
#pragma unroll
        for (int off = 1; off < 16; off <<= 1)
          rmax = fmaxf(rmax, __shfl_xor(rmax, off, 64));
        float mold = mst[mi][r];
        float mnew = fmaxf(mold, rmax);
        float alpha = __expf(mold - mnew);
        float rsum = 0.f;
#pragma unroll
        for (int ni = 0; ni < 4; ++ni) {
          float p = __expf(sacc[mi][ni][r] - mnew);
          sacc[mi][ni][r] = p;
          rsum += p;
        }
#pragma unroll
        for (int off = 1; off < 16; off <<= 1)
          rsum += __shfl_xor(rsum, off, 64);
        mst[mi][r] = mnew;
        lst[mi][r] = lst[mi][r] * alpha + rsum;
#pragma unroll
        for (int ni = 0; ni < 4; ++ni)
          oacc[mi][ni][r] *= alpha;
      }
    }

    // P: C-layout -> A-operand layout via per-wave LDS round-trip
#pragma unroll
    for (int mi = 0; mi < 2; ++mi)
#pragma unroll
      for (int ni = 0; ni < 4; ++ni)
#pragma unroll
        for (int r = 0; r < 4; ++r)
          lP[wave][mi * 16 + quad * 4 + r][ni * 16 + l16] = f2bf(sacc[mi][ni][r]);

    __syncthreads();

    // O += P @ V
#pragma unroll
    for (int ks = 0; ks < 2; ++ks) {
      s16x8 pf[2], vf[4];
#pragma unroll
      for (int mi = 0; mi < 2; ++mi)
        pf[mi] = *(const s16x8*)&lP[wave][mi * 16 + l16][ks * 32 + quad * 8];
#pragma unroll
      for (int ni = 0; ni < 4; ++ni)
        vf[ni] = *(const s16x8*)&lVt[ni * 16 + l16][ks * 32 + quad * 8];
#pragma unroll
      for (int mi = 0; mi < 2; ++mi)
#pragma unroll
        for (int ni = 0; ni < 4; ++ni)
          oacc[mi][ni] = mfma16(pf[mi], vf[ni], oacc[mi][ni]);
    }
  }

  // epilogue: O/(l) -> (B,S,D) bf16
  const int bb = bh >> 4, h = bh & 15;
#pragma unroll
  for (int mi = 0; mi < 2; ++mi) {
#pragma unroll
    for (int r = 0; r < 4; ++r) {
      float inv = 1.0f / lst[mi][r];
      int srow = q0 + mi * 16 + quad * 4 + r;
#pragma unroll
      for (int ni = 0; ni < 4; ++ni) {
        int col = h * DKc + ni * 16 + l16;
        O[((size_t)(bb * Sc + srow)) * Dc + col] = f2bf(oacc[mi][ni][r] * inv);
      }
    }
  }
}

// ---------------- launch -----------------------------------------------------
extern "C" void kernel_launch(void* const* d_in, const int* in_sizes, int n_in,
                              void* d_out, int out_size, void* d_ws, size_t ws_size,
                              hipStream_t stream) {
  const void* x  = d_in[0];
  const void* wq = d_in[1]; const void* bq = d_in[2];
  const void* wk = d_in[3]; const void* bk = d_in[4];
  const void* wv = d_in[5]; const void* bv = d_in[6];
  const void* wo = d_in[7]; const void* bo = d_in[8];

  char* wsb = (char*)d_ws;
  int*   flag = (int*)wsb;
  short* x_c  = (short*)(wsb + 1024);                       // 4M bf16
  short* w_c  = x_c + (size_t)4 * 1024 * 1024;              // 4 x 1M bf16 (q,k,v,o)
  float* b_c  = (float*)(wsb + 1024 + 16 * 1024 * 1024);    // 4 x 1024 fp32
  short* Qc   = (short*)(wsb + 1024 + 16 * 1024 * 1024 + 16384);
  short* Kc   = Qc + (size_t)4 * 1024 * 1024;
  short* Vc   = Kc + (size_t)4 * 1024 * 1024;
  short* Oc   = Vc + (size_t)4 * 1024 * 1024;
  // total ws use: ~50.4 MB

  detect_ker<<<1, 256, 0, stream>>>((const unsigned short*)x, flag);

  norm_bf<<<4096, 256, 0, stream>>>(x,  x_c, 1048576, flag);
  norm_bf<<<1024, 256, 0, stream>>>(wq, w_c + 0 * 1048576, 262144, flag);
  norm_bf<<<1024, 256, 0, stream>>>(wk, w_c + 1 * 1048576, 262144, flag);
  norm_bf<<<1024, 256, 0, stream>>>(wv, w_c + 2 * 1048576, 262144, flag);
  norm_bf<<<1024, 256, 0, stream>>>(wo, w_c + 3 * 1048576, 262144, flag);
  norm_bias<<<1, 256, 0, stream>>>(bq, b_c + 0 * 1024, flag);
  norm_bias<<<1, 256, 0, stream>>>(bk, b_c + 1 * 1024, flag);
  norm_bias<<<1, 256, 0, stream>>>(bv, b_c + 2 * 1024, flag);
  norm_bias<<<1, 256, 0, stream>>>(bo, b_c + 3 * 1024, flag);

  // QKV projection (z = 0,1,2 -> Q,K,V); Q scaled by 1/sqrt(DK)
  gemm_bt<0><<<dim3(8, 32, 3), 256, 0, stream>>>(x_c, w_c, b_c, Qc, nullptr, flag);

  // attention
  attn_ker<<<dim3(16, 32), 256, 0, stream>>>(Qc, Kc, Vc, Oc);

  // output projection -> d_out (dtype per flag)
  gemm_bt<1><<<dim3(8, 32, 1), 256, 0, stream>>>(Oc, w_c + 3 * 1048576,
                                                 b_c + 3 * 1024, nullptr, d_out, flag);
}